// Round 4
// baseline (30.304 us; speedup 1.0000x reference)
//
#include <hip/hip_runtime.h>
#include <math.h>

#define IN_H 104
#define IN_W 104
#define BSZ 16
#define NT 50
#define SUB 6
#define FEPS 1e-7f
#define CS (IN_H * IN_W)            // 10816
#define CELLS (3 * CS)              // 32448
#define DBLK 256
#define CPT 4
#define NBX ((CELLS + DBLK * CPT - 1) / (DBLK * CPT))   // 32
#define NBLOCKS (NBX * BSZ)         // 512

// scaled anchors = ANCHORS / 8  (stride = 832/104 = 8)
__constant__ float c_aw[9] = {1.25f, 2.0f, 4.125f, 3.75f, 7.75f, 7.375f, 14.5f, 19.5f, 46.625f};
__constant__ float c_ah[9] = {1.625f, 3.75f, 2.875f, 7.625f, 5.625f, 14.875f, 11.25f, 24.75f, 40.75f};

__device__ __forceinline__ float clampp(float v) {
    return fminf(fmaxf(v, FEPS), 1.0f - FEPS);
}

__device__ __forceinline__ float fsig(float v) {        // sigmoid, fast
    return __fdividef(1.0f, 1.0f + __expf(-v));
}

// Returns 3*inter - areab.  noobj test:  max_t(...) <= areaa
//   (IoU > 0.5  <=>  2*inter > union  <=>  3*inter - areab > areaa)
__device__ __forceinline__ float iou_part(float4 bx, float ab,
                                          float ax1, float ay1, float ax2, float ay2) {
    float mnx = fmaxf(ax1, bx.x), mny = fmaxf(ay1, bx.y);
    float mxx = fminf(ax2, bx.z), mxy = fminf(ay2, bx.w);
    float iw = fmaxf(mxx - mnx, 0.0f), ih = fmaxf(mxy - mny, 0.0f);
    return fmaf(iw * ih, 3.0f, -ab);
}

__global__ __launch_bounds__(DBLK) void yolo_fused_kernel(const float* __restrict__ in,
                                                          const float* __restrict__ tgt,
                                                          float* __restrict__ g_part,
                                                          unsigned int* __restrict__ g_cnt,
                                                          float* __restrict__ out) {
    const int bx  = blockIdx.x;
    const int b   = blockIdx.y;
    const int tid = threadIdx.x;
    const bool isb0 = (bx == 0);

    __shared__ float4 s_box[NT];
    __shared__ float  s_ab[NT];
    __shared__ int    s_code[NT];

    int   code = -1, bn = 0, gi = 0, gj = 0;
    float gx = 0.f, gy = 0.f, gw = 0.f, gh = 0.f, t2v = 0.f, t3v = 0.f;

    if (tid < NT) {
        const float* tp = tgt + (size_t)(b * NT + tid) * 5;
        float t0 = tp[0], t1 = tp[1];
        t2v = tp[2]; t3v = tp[3];
        gx = t0 * IN_W; gy = t1 * IN_H; gw = t2v * IN_W; gh = t3v * IN_H;
        s_box[tid] = make_float4(gx - gw * 0.5f, gy - gh * 0.5f,
                                 gx + gw * 0.5f, gy + gh * 0.5f);
        s_ab[tid] = gw * gh;
        if (isb0) {
            float best = -1e30f;
            #pragma unroll
            for (int k = 0; k < 9; ++k) {
                float aw = c_aw[k], ah = c_ah[k];
                float inter = fminf(gw, aw) * fminf(gh, ah);
                float uni   = gw * gh + aw * ah - inter;
                float r = __fdividef(inter, uni);
                if (r > best) { best = r; bn = k; }
            }
            gi = (int)floorf(gx);
            gj = (int)floorf(gy);
            bool valid = (bn >= SUB) && (bn < SUB + 3) &&
                         (gj < IN_H) && (gi < IN_W) && (gi >= 0) && (gj >= 0);
            code = valid ? ((bn - SUB) * CS + gj * IN_W + gi) : -1;
            s_code[tid] = code;
        }
    }
    __syncthreads();

    // ---- dense noobj part: CPT cells per thread ----
    const int c0 = bx * (DBLK * CPT) + tid;

    float ax1[CPT], ay1[CPT], ax2[CPT], ay2[CPT], areaa[CPT], nlog[CPT], worst[CPT];
    #pragma unroll
    for (int q = 0; q < CPT; ++q) {
        const int c = c0 + q * DBLK;
        ax1[q] = 0.f; ay1[q] = 0.f; ax2[q] = 0.f; ay2[q] = 0.f;
        areaa[q] = -1e30f; nlog[q] = 0.f; worst[q] = 0.f;   // worst > areaa => no contrib for pad lanes
        if (c < CELLS) {
            const int a = c / CS;
            const int r = c - a * CS;
            const int j = r / IN_W;
            const int i = r - j * IN_W;
            const size_t base = ((size_t)b * 18 + (size_t)a * 6) * CS + r;
            float v0 = in[base];
            float v1 = in[base + CS];
            float v2 = in[base + 2 * CS];
            float v3 = in[base + 3 * CS];
            float v4 = in[base + 4 * CS];

            float sx   = fsig(v0);
            float sy   = fsig(v1);
            float conf = fsig(v4);
            float pw = __expf(v2) * c_aw[SUB + a];
            float ph = __expf(v3) * c_ah[SUB + a];
            float px = sx + (float)i, py = sy + (float)j;
            ax1[q] = px - pw * 0.5f; ay1[q] = py - ph * 0.5f;
            ax2[q] = px + pw * 0.5f; ay2[q] = py + ph * 0.5f;
            areaa[q] = pw * ph;
            nlog[q] = -__logf(1.0f - clampp(conf));
            worst[q] = -1e30f;
        }
    }

    #pragma unroll 2
    for (int t = 0; t < NT; ++t) {
        float4 bxv = s_box[t];
        float  ab  = s_ab[t];
        #pragma unroll
        for (int q = 0; q < CPT; ++q)
            worst[q] = fmaxf(worst[q], iou_part(bxv, ab, ax1[q], ay1[q], ax2[q], ay2[q]));
    }

    float contrib = 0.0f;
    #pragma unroll
    for (int q = 0; q < CPT; ++q)
        contrib += (worst[q] <= areaa[q]) ? nlog[q] : 0.0f;

    // ---- positive (masked-cell) losses: block x==0 only, folded into contrib ----
    if (isb0 && tid < NT) {
        bool winner = (code >= 0);
        for (int u = tid + 1; u < NT; ++u) winner = winner && (s_code[u] != code);

        if (winner) {
            const int a = bn - SUB;
            const size_t base = (((size_t)b * 18 + (size_t)a * 6) * IN_H + gj) * IN_W + gi;
            float v0 = in[base];
            float v1 = in[base + CS];
            float v2 = in[base + 2 * CS];
            float v3 = in[base + 3 * CS];
            float v4 = in[base + 4 * CS];
            float v5 = in[base + 5 * CS];

            float sx   = fsig(v0);
            float sy   = fsig(v1);
            float conf = fsig(v4);
            float scls = fsig(v5);

            float x_c = clampp(sx), y_c = clampp(sy);
            float conf_c = clampp(conf), cls_c = clampp(scls);

            float txv = gx - floorf(gx), tyv = gy - floorf(gy);
            float twv = __logf(__fdividef(fmaxf(gw, FEPS), c_aw[bn]));
            float thv = __logf(__fdividef(fmaxf(gh, FEPS), c_ah[bn]));
            float bls = 2.0f - t2v * t3v;

            float lbx = -txv * __logf(x_c) - (1.0f - txv) * __logf(1.0f - x_c);
            float lby = -tyv * __logf(y_c) - (1.0f - tyv) * __logf(1.0f - y_c);
            float dw = v2 - twv, dh = v3 - thv;

            float pos = (lbx + lby) * bls
                      + 0.5f * (dw * dw + dh * dh) * bls
                      - __logf(conf_c)      // bce(conf, 1) * mask
                      - __logf(cls_c);      // bce(cls, 1) * mask (tcls = 1)

            // cancel this block-grid's noobj term for this cell if it fires there
            // (identical op sequence => bit-identical decision & value)
            float pw = __expf(v2) * c_aw[SUB + a];
            float ph = __expf(v3) * c_ah[SUB + a];
            float px = sx + (float)gi, py = sy + (float)gj;
            float a1x = px - pw * 0.5f, a1y = py - ph * 0.5f;
            float a2x = px + pw * 0.5f, a2y = py + ph * 0.5f;
            float areap = pw * ph;
            float w2 = -1e30f;
            for (int u = 0; u < NT; ++u)
                w2 = fmaxf(w2, iou_part(s_box[u], s_ab[u], a1x, a1y, a2x, a2y));
            if (w2 <= areap) pos += __logf(1.0f - conf_c);

            contrib += pos;
        }
    }
    contrib *= (1.0f / (float)BSZ);

    // ---- block reduction ----
    for (int o = 32; o > 0; o >>= 1)
        contrib += __shfl_down(contrib, o, 64);

    __shared__ float s_p[DBLK / 64];
    __shared__ int   s_last;
    if ((tid & 63) == 0) s_p[tid >> 6] = contrib;
    __syncthreads();
    if (tid == 0) {
        float tot = s_p[0] + s_p[1] + s_p[2] + s_p[3];
        const int bid = b * NBX + bx;
        __hip_atomic_store(&g_part[bid], tot, __ATOMIC_RELAXED, __HIP_MEMORY_SCOPE_AGENT);
        unsigned int old = __hip_atomic_fetch_add(g_cnt, 1u, __ATOMIC_ACQ_REL,
                                                  __HIP_MEMORY_SCOPE_AGENT);
        s_last = (old == NBLOCKS - 1);
    }
    __syncthreads();

    // ---- last block: final reduce (all partials visible via release chain on g_cnt) ----
    if (s_last) {
        float s = __hip_atomic_load(&g_part[tid], __ATOMIC_RELAXED, __HIP_MEMORY_SCOPE_AGENT)
                + __hip_atomic_load(&g_part[tid + DBLK], __ATOMIC_RELAXED, __HIP_MEMORY_SCOPE_AGENT);
        for (int o = 32; o > 0; o >>= 1)
            s += __shfl_down(s, o, 64);
        if ((tid & 63) == 0) s_p[tid >> 6] = s;
        __syncthreads();
        if (tid == 0) out[0] = s_p[0] + s_p[1] + s_p[2] + s_p[3];
    }
}

extern "C" void kernel_launch(void* const* d_in, const int* in_sizes, int n_in,
                              void* d_out, int out_size, void* d_ws, size_t ws_size,
                              hipStream_t stream) {
    const float* in  = (const float*)d_in[0];   // (16, 18, 104, 104) f32
    const float* tgt = (const float*)d_in[1];   // (16, 50, 5) f32
    float* out = (float*)d_out;

    unsigned int* g_cnt  = (unsigned int*)d_ws;                 // 4 B counter
    float*        g_part = (float*)((char*)d_ws + 256);         // 512 floats

    // counter must be 0 at kernel start regardless of prior buffer state
    hipMemsetAsync(d_ws, 0, 4, stream);
    yolo_fused_kernel<<<dim3(NBX, BSZ), DBLK, 0, stream>>>(in, tgt, g_part, g_cnt, out);
}

// Round 5
// 29.166 us; speedup vs baseline: 1.0390x; 1.0390x over previous
//
#include <hip/hip_runtime.h>
#include <math.h>

#define IN_H 104
#define IN_W 104
#define BSZ 16
#define NT 50
#define SUB 6
#define FEPS 1e-7f
#define CS (IN_H * IN_W)            // 10816
#define CELLS (3 * CS)              // 32448
#define DBLK 256
#define CPT 4
#define NBX ((CELLS + DBLK * CPT - 1) / (DBLK * CPT))   // 32

// scaled anchors = ANCHORS / 8  (stride = 832/104 = 8)
__constant__ float c_aw[9] = {1.25f, 2.0f, 4.125f, 3.75f, 7.75f, 7.375f, 14.5f, 19.5f, 46.625f};
__constant__ float c_ah[9] = {1.625f, 3.75f, 2.875f, 7.625f, 5.625f, 14.875f, 11.25f, 24.75f, 40.75f};

__device__ __forceinline__ float clampp(float v) {
    return fminf(fmaxf(v, FEPS), 1.0f - FEPS);
}

__device__ __forceinline__ float fsig(float v) {        // sigmoid, fast
    return __fdividef(1.0f, 1.0f + __expf(-v));
}

// Returns 3*inter - areab.  noobj test:  max_t(...) <= areaa
//   (IoU > 0.5  <=>  2*inter > union  <=>  3*inter - areab > areaa)
__device__ __forceinline__ float iou_part(float4 bx, float ab,
                                          float ax1, float ay1, float ax2, float ay2) {
    float mnx = fmaxf(ax1, bx.x), mny = fmaxf(ay1, bx.y);
    float mxx = fminf(ax2, bx.z), mxy = fminf(ay2, bx.w);
    float iw = fmaxf(mxx - mnx, 0.0f), ih = fmaxf(mxy - mny, 0.0f);
    return fmaf(iw * ih, 3.0f, -ab);
}

__global__ __launch_bounds__(DBLK) void yolo_fused_kernel(const float* __restrict__ in,
                                                          const float* __restrict__ tgt,
                                                          float* __restrict__ out) {
    const int bx  = blockIdx.x;
    const int b   = blockIdx.y;
    const int tid = threadIdx.x;
    const bool isb0 = (bx == 0);

    __shared__ float4 s_box[NT];
    __shared__ float  s_ab[NT];
    __shared__ int    s_code[NT];

    int   code = -1, bn = 0, gi = 0, gj = 0;
    float gx = 0.f, gy = 0.f, gw = 0.f, gh = 0.f, t2v = 0.f, t3v = 0.f;

    if (tid < NT) {
        const float* tp = tgt + (size_t)(b * NT + tid) * 5;
        float t0 = tp[0], t1 = tp[1];
        t2v = tp[2]; t3v = tp[3];
        gx = t0 * IN_W; gy = t1 * IN_H; gw = t2v * IN_W; gh = t3v * IN_H;
        s_box[tid] = make_float4(gx - gw * 0.5f, gy - gh * 0.5f,
                                 gx + gw * 0.5f, gy + gh * 0.5f);
        s_ab[tid] = gw * gh;
        if (isb0) {
            float best = -1e30f;
            #pragma unroll
            for (int k = 0; k < 9; ++k) {
                float aw = c_aw[k], ah = c_ah[k];
                float inter = fminf(gw, aw) * fminf(gh, ah);
                float uni   = gw * gh + aw * ah - inter;
                float r = __fdividef(inter, uni);
                if (r > best) { best = r; bn = k; }
            }
            gi = (int)floorf(gx);
            gj = (int)floorf(gy);
            bool valid = (bn >= SUB) && (bn < SUB + 3) &&
                         (gj < IN_H) && (gi < IN_W) && (gi >= 0) && (gj >= 0);
            code = valid ? ((bn - SUB) * CS + gj * IN_W + gi) : -1;
            s_code[tid] = code;
        }
    }
    __syncthreads();

    // ---- dense noobj part: CPT cells per thread ----
    const int c0 = bx * (DBLK * CPT) + tid;

    float ax1[CPT], ay1[CPT], ax2[CPT], ay2[CPT], areaa[CPT], nlog[CPT], worst[CPT];
    #pragma unroll
    for (int q = 0; q < CPT; ++q) {
        const int c = c0 + q * DBLK;
        ax1[q] = 0.f; ay1[q] = 0.f; ax2[q] = 0.f; ay2[q] = 0.f;
        areaa[q] = -1e30f; nlog[q] = 0.f; worst[q] = 0.f;   // pad lanes: worst > areaa => no contrib
        if (c < CELLS) {
            const int a = c / CS;
            const int r = c - a * CS;
            const int j = r / IN_W;
            const int i = r - j * IN_W;
            const size_t base = ((size_t)b * 18 + (size_t)a * 6) * CS + r;
            float v0 = in[base];
            float v1 = in[base + CS];
            float v2 = in[base + 2 * CS];
            float v3 = in[base + 3 * CS];
            float v4 = in[base + 4 * CS];

            float sx   = fsig(v0);
            float sy   = fsig(v1);
            float conf = fsig(v4);
            float pw = __expf(v2) * c_aw[SUB + a];
            float ph = __expf(v3) * c_ah[SUB + a];
            float px = sx + (float)i, py = sy + (float)j;
            ax1[q] = px - pw * 0.5f; ay1[q] = py - ph * 0.5f;
            ax2[q] = px + pw * 0.5f; ay2[q] = py + ph * 0.5f;
            areaa[q] = pw * ph;
            nlog[q] = -__logf(1.0f - clampp(conf));
            worst[q] = -1e30f;
        }
    }

    #pragma unroll 2
    for (int t = 0; t < NT; ++t) {
        float4 bxv = s_box[t];
        float  ab  = s_ab[t];
        #pragma unroll
        for (int q = 0; q < CPT; ++q)
            worst[q] = fmaxf(worst[q], iou_part(bxv, ab, ax1[q], ay1[q], ax2[q], ay2[q]));
    }

    float contrib = 0.0f;
    #pragma unroll
    for (int q = 0; q < CPT; ++q)
        contrib += (worst[q] <= areaa[q]) ? nlog[q] : 0.0f;

    // ---- positive (masked-cell) losses: block x==0 only, folded into contrib ----
    if (isb0 && tid < NT) {
        bool winner = (code >= 0);
        for (int u = tid + 1; u < NT; ++u) winner = winner && (s_code[u] != code);

        if (winner) {
            const int a = bn - SUB;
            const size_t base = (((size_t)b * 18 + (size_t)a * 6) * IN_H + gj) * IN_W + gi;
            float v0 = in[base];
            float v1 = in[base + CS];
            float v2 = in[base + 2 * CS];
            float v3 = in[base + 3 * CS];
            float v4 = in[base + 4 * CS];
            float v5 = in[base + 5 * CS];

            float sx   = fsig(v0);
            float sy   = fsig(v1);
            float conf = fsig(v4);
            float scls = fsig(v5);

            float x_c = clampp(sx), y_c = clampp(sy);
            float conf_c = clampp(conf), cls_c = clampp(scls);

            float txv = gx - floorf(gx), tyv = gy - floorf(gy);
            float twv = __logf(__fdividef(fmaxf(gw, FEPS), c_aw[bn]));
            float thv = __logf(__fdividef(fmaxf(gh, FEPS), c_ah[bn]));
            float bls = 2.0f - t2v * t3v;

            float lbx = -txv * __logf(x_c) - (1.0f - txv) * __logf(1.0f - x_c);
            float lby = -tyv * __logf(y_c) - (1.0f - tyv) * __logf(1.0f - y_c);
            float dw = v2 - twv, dh = v3 - thv;

            float pos = (lbx + lby) * bls
                      + 0.5f * (dw * dw + dh * dh) * bls
                      - __logf(conf_c)      // bce(conf, 1) * mask
                      - __logf(cls_c);      // bce(cls, 1) * mask (tcls = 1)

            // cancel the dense noobj term for this cell if it fires there
            // (identical op sequence => bit-identical decision & value)
            float pw = __expf(v2) * c_aw[SUB + a];
            float ph = __expf(v3) * c_ah[SUB + a];
            float px = sx + (float)gi, py = sy + (float)gj;
            float a1x = px - pw * 0.5f, a1y = py - ph * 0.5f;
            float a2x = px + pw * 0.5f, a2y = py + ph * 0.5f;
            float areap = pw * ph;
            float w2 = -1e30f;
            for (int u = 0; u < NT; ++u)
                w2 = fmaxf(w2, iou_part(s_box[u], s_ab[u], a1x, a1y, a2x, a2y));
            if (w2 <= areap) pos += __logf(1.0f - conf_c);

            contrib += pos;
        }
    }
    contrib *= (1.0f / (float)BSZ);

    // ---- block reduction: wave64 shuffle + LDS across 4 waves, one atomic per block ----
    for (int o = 32; o > 0; o >>= 1)
        contrib += __shfl_down(contrib, o, 64);

    __shared__ float s_p[DBLK / 64];
    if ((tid & 63) == 0) s_p[tid >> 6] = contrib;
    __syncthreads();
    if (tid == 0) {
        float tot = s_p[0] + s_p[1] + s_p[2] + s_p[3];
        atomicAdd(out, tot);
    }
}

extern "C" void kernel_launch(void* const* d_in, const int* in_sizes, int n_in,
                              void* d_out, int out_size, void* d_ws, size_t ws_size,
                              hipStream_t stream) {
    const float* in  = (const float*)d_in[0];   // (16, 18, 104, 104) f32
    const float* tgt = (const float*)d_in[1];   // (16, 50, 5) f32
    float* out = (float*)d_out;

    hipMemsetAsync(out, 0, sizeof(float), stream);      // tiny node: out must start at 0
    yolo_fused_kernel<<<dim3(NBX, BSZ), DBLK, 0, stream>>>(in, tgt, out);
}

// Round 6
// 25.804 us; speedup vs baseline: 1.1744x; 1.1303x over previous
//
#include <hip/hip_runtime.h>
#include <math.h>

#define IN_H 104
#define IN_W 104
#define BSZ 16
#define NT 50
#define SUB 6
#define FEPS 1e-7f
#define CS (IN_H * IN_W)            // 10816
#define CELLS (3 * CS)              // 32448
#define DBLK 256
#define CPT 4
#define NBX ((CELLS + DBLK * CPT - 1) / (DBLK * CPT))   // 32
#define NPART (BSZ * NBX)           // 512

// scaled anchors = ANCHORS / 8  (stride = 832/104 = 8)
__constant__ float c_aw[9] = {1.25f, 2.0f, 4.125f, 3.75f, 7.75f, 7.375f, 14.5f, 19.5f, 46.625f};
__constant__ float c_ah[9] = {1.625f, 3.75f, 2.875f, 7.625f, 5.625f, 14.875f, 11.25f, 24.75f, 40.75f};

__device__ __forceinline__ float clampp(float v) {
    return fminf(fmaxf(v, FEPS), 1.0f - FEPS);
}

__device__ __forceinline__ float fsig(float v) {        // sigmoid, fast
    return __fdividef(1.0f, 1.0f + __expf(-v));
}

// Returns 3*inter - areab.  noobj test:  max_t(...) <= areaa
//   (IoU > 0.5  <=>  2*inter > union  <=>  3*inter - areab > areaa)
__device__ __forceinline__ float iou_part(float4 bx, float ab,
                                          float ax1, float ay1, float ax2, float ay2) {
    float mnx = fmaxf(ax1, bx.x), mny = fmaxf(ay1, bx.y);
    float mxx = fminf(ax2, bx.z), mxy = fminf(ay2, bx.w);
    float iw = fmaxf(mxx - mnx, 0.0f), ih = fmaxf(mxy - mny, 0.0f);
    return fmaf(iw * ih, 3.0f, -ab);
}

__global__ __launch_bounds__(DBLK) void yolo_fused_kernel(const float* __restrict__ in,
                                                          const float* __restrict__ tgt,
                                                          float* __restrict__ g_part) {
    const int bx  = blockIdx.x;
    const int b   = blockIdx.y;
    const int tid = threadIdx.x;
    const bool isb0 = (bx == 0);

    __shared__ float4 s_box[NT];
    __shared__ float  s_ab[NT];
    __shared__ int    s_code[NT];

    int   code = -1, bn = 0, gi = 0, gj = 0;
    float gx = 0.f, gy = 0.f, gw = 0.f, gh = 0.f, t2v = 0.f, t3v = 0.f;

    if (tid < NT) {
        const float* tp = tgt + (size_t)(b * NT + tid) * 5;
        float t0 = tp[0], t1 = tp[1];
        t2v = tp[2]; t3v = tp[3];
        gx = t0 * IN_W; gy = t1 * IN_H; gw = t2v * IN_W; gh = t3v * IN_H;
        s_box[tid] = make_float4(gx - gw * 0.5f, gy - gh * 0.5f,
                                 gx + gw * 0.5f, gy + gh * 0.5f);
        s_ab[tid] = gw * gh;
        if (isb0) {
            float best = -1e30f;
            #pragma unroll
            for (int k = 0; k < 9; ++k) {
                float aw = c_aw[k], ah = c_ah[k];
                float inter = fminf(gw, aw) * fminf(gh, ah);
                float uni   = gw * gh + aw * ah - inter;
                float r = __fdividef(inter, uni);
                if (r > best) { best = r; bn = k; }
            }
            gi = (int)floorf(gx);
            gj = (int)floorf(gy);
            bool valid = (bn >= SUB) && (bn < SUB + 3) &&
                         (gj < IN_H) && (gi < IN_W) && (gi >= 0) && (gj >= 0);
            code = valid ? ((bn - SUB) * CS + gj * IN_W + gi) : -1;
            s_code[tid] = code;
        }
    }
    __syncthreads();

    // ---- dense noobj part: CPT cells per thread ----
    const int c0 = bx * (DBLK * CPT) + tid;

    float ax1[CPT], ay1[CPT], ax2[CPT], ay2[CPT], areaa[CPT], nlog[CPT], worst[CPT];
    #pragma unroll
    for (int q = 0; q < CPT; ++q) {
        const int c = c0 + q * DBLK;
        ax1[q] = 0.f; ay1[q] = 0.f; ax2[q] = 0.f; ay2[q] = 0.f;
        areaa[q] = -1e30f; nlog[q] = 0.f; worst[q] = 0.f;   // pad lanes: worst > areaa => no contrib
        if (c < CELLS) {
            const int a = c / CS;
            const int r = c - a * CS;
            const int j = r / IN_W;
            const int i = r - j * IN_W;
            const size_t base = ((size_t)b * 18 + (size_t)a * 6) * CS + r;
            float v0 = in[base];
            float v1 = in[base + CS];
            float v2 = in[base + 2 * CS];
            float v3 = in[base + 3 * CS];
            float v4 = in[base + 4 * CS];

            float sx   = fsig(v0);
            float sy   = fsig(v1);
            float conf = fsig(v4);
            float pw = __expf(v2) * c_aw[SUB + a];
            float ph = __expf(v3) * c_ah[SUB + a];
            float px = sx + (float)i, py = sy + (float)j;
            ax1[q] = px - pw * 0.5f; ay1[q] = py - ph * 0.5f;
            ax2[q] = px + pw * 0.5f; ay2[q] = py + ph * 0.5f;
            areaa[q] = pw * ph;
            nlog[q] = -__logf(1.0f - clampp(conf));
            worst[q] = -1e30f;
        }
    }

    #pragma unroll 2
    for (int t = 0; t < NT; ++t) {
        float4 bxv = s_box[t];
        float  ab  = s_ab[t];
        #pragma unroll
        for (int q = 0; q < CPT; ++q)
            worst[q] = fmaxf(worst[q], iou_part(bxv, ab, ax1[q], ay1[q], ax2[q], ay2[q]));
    }

    float contrib = 0.0f;
    #pragma unroll
    for (int q = 0; q < CPT; ++q)
        contrib += (worst[q] <= areaa[q]) ? nlog[q] : 0.0f;

    // ---- positive (masked-cell) losses: block x==0 only, folded into contrib ----
    if (isb0 && tid < NT) {
        bool winner = (code >= 0);
        for (int u = tid + 1; u < NT; ++u) winner = winner && (s_code[u] != code);

        if (winner) {
            const int a = bn - SUB;
            const size_t base = (((size_t)b * 18 + (size_t)a * 6) * IN_H + gj) * IN_W + gi;
            float v0 = in[base];
            float v1 = in[base + CS];
            float v2 = in[base + 2 * CS];
            float v3 = in[base + 3 * CS];
            float v4 = in[base + 4 * CS];
            float v5 = in[base + 5 * CS];

            float sx   = fsig(v0);
            float sy   = fsig(v1);
            float conf = fsig(v4);
            float scls = fsig(v5);

            float x_c = clampp(sx), y_c = clampp(sy);
            float conf_c = clampp(conf), cls_c = clampp(scls);

            float txv = gx - floorf(gx), tyv = gy - floorf(gy);
            float twv = __logf(__fdividef(fmaxf(gw, FEPS), c_aw[bn]));
            float thv = __logf(__fdividef(fmaxf(gh, FEPS), c_ah[bn]));
            float bls = 2.0f - t2v * t3v;

            float lbx = -txv * __logf(x_c) - (1.0f - txv) * __logf(1.0f - x_c);
            float lby = -tyv * __logf(y_c) - (1.0f - tyv) * __logf(1.0f - y_c);
            float dw = v2 - twv, dh = v3 - thv;

            float pos = (lbx + lby) * bls
                      + 0.5f * (dw * dw + dh * dh) * bls
                      - __logf(conf_c)      // bce(conf, 1) * mask
                      - __logf(cls_c);      // bce(cls, 1) * mask (tcls = 1)

            // cancel the dense noobj term for this cell if it fires there
            // (identical op sequence => bit-identical decision & value)
            float pw = __expf(v2) * c_aw[SUB + a];
            float ph = __expf(v3) * c_ah[SUB + a];
            float px = sx + (float)gi, py = sy + (float)gj;
            float a1x = px - pw * 0.5f, a1y = py - ph * 0.5f;
            float a2x = px + pw * 0.5f, a2y = py + ph * 0.5f;
            float areap = pw * ph;
            float w2 = -1e30f;
            for (int u = 0; u < NT; ++u)
                w2 = fmaxf(w2, iou_part(s_box[u], s_ab[u], a1x, a1y, a2x, a2y));
            if (w2 <= areap) pos += __logf(1.0f - conf_c);

            contrib += pos;
        }
    }
    contrib *= (1.0f / (float)BSZ);

    // ---- block reduction: wave64 shuffle + LDS across 4 waves, one plain store per block ----
    for (int o = 32; o > 0; o >>= 1)
        contrib += __shfl_down(contrib, o, 64);

    __shared__ float s_p[DBLK / 64];
    if ((tid & 63) == 0) s_p[tid >> 6] = contrib;
    __syncthreads();
    if (tid == 0)
        g_part[b * NBX + bx] = s_p[0] + s_p[1] + s_p[2] + s_p[3];
}

// ---------------- final reduce: 512 floats -> out[0] ----------------
__global__ __launch_bounds__(256) void reduce_kernel(const float* __restrict__ g_part,
                                                     float* __restrict__ out) {
    const int tid = threadIdx.x;
    float s = g_part[tid] + g_part[tid + 256];

    for (int o = 32; o > 0; o >>= 1)
        s += __shfl_down(s, o, 64);

    __shared__ float s_p[4];
    if ((tid & 63) == 0) s_p[tid >> 6] = s;
    __syncthreads();
    if (tid == 0) out[0] = s_p[0] + s_p[1] + s_p[2] + s_p[3];
}

extern "C" void kernel_launch(void* const* d_in, const int* in_sizes, int n_in,
                              void* d_out, int out_size, void* d_ws, size_t ws_size,
                              hipStream_t stream) {
    const float* in  = (const float*)d_in[0];   // (16, 18, 104, 104) f32
    const float* tgt = (const float*)d_in[1];   // (16, 50, 5) f32
    float* out = (float*)d_out;

    float* g_part = (float*)d_ws;               // 512 floats, fully rewritten every call

    yolo_fused_kernel<<<dim3(NBX, BSZ), DBLK, 0, stream>>>(in, tgt, g_part);
    reduce_kernel<<<1, 256, 0, stream>>>(g_part, out);
}